// Round 22
// baseline (1965.703 us; speedup 1.0000x reference)
//
#include <hip/hip_runtime.h>
#include <hip/hip_bf16.h>

// ThinkSortTransformer fused kernel, MI355X (gfx950).
// r22 = r19/r21 minus gbase (16 persistent regs freed -> less spill; G's
// orig-half recomputed per step: 8 single-term MFMAs + 8 L1-hot loads).
// Inputs f32, output f32. One batch per 256-thread block, LDS ~49KB ->
// 3 blocks/CU (launch_bounds(256,3)). Softmax row-sum via MFMA (E@ones);
// unnormalized E (shift-invariant, |s|<<88); normalize after PV with rcp.
// setprio; rcp sigmoid; SCALE folded into q.
// h bf16 hi/lo -> G 3-term; QKV/FFN 2-term.

typedef unsigned short ushort_t;
using short8  = __attribute__((ext_vector_type(8))) short;
using floatx4 = __attribute__((ext_vector_type(4))) float;

#define MFMA(a,b,c) __builtin_amdgcn_mfma_f32_16x16x32_bf16((a),(b),(c),0,0,0)
#define LD8(base, idx) (*(const short8*)((base) + (idx)))
#define PRIO1() __builtin_amdgcn_s_setprio(1)
#define PRIO0() __builtin_amdgcn_s_setprio(0)

__device__ __forceinline__ float bf2f(ushort_t u){ return __uint_as_float(((unsigned)u)<<16); }
__device__ __forceinline__ ushort_t f2bf(float f){
  unsigned u = __float_as_uint(f);
  u += 0x7fffu + ((u>>16)&1u);           // round-to-nearest-even
  return (ushort_t)(u>>16);
}
__device__ __forceinline__ float rcpf(float x){ return __builtin_amdgcn_rcpf(x); }
// split-store: hi + lo bf16 (self-correcting: lo = RNE(x - hi))
__device__ __forceinline__ void st2(ushort_t* ph, ushort_t* pl, int idx, float x){
  ushort_t h = f2bf(x);
  ph[idx] = h;
  pl[idx] = f2bf(x - bf2f(h));
}
__device__ __forceinline__ short8 zero8(){
  short8 v; v[0]=0;v[1]=0;v[2]=0;v[3]=0;v[4]=0;v[5]=0;v[6]=0;v[7]=0; return v;
}
__device__ __forceinline__ short8 ones8bf(){
  short8 v;
  #pragma unroll
  for (int e=0;e<8;++e) v[e] = (short)0x3F80;   // bf16 1.0
  return v;
}
// GELU via Abramowitz-Stegun 7.1.25 erf approx (|err| <= 2.5e-5 << bf16 eps)
__device__ __forceinline__ float gelu_f(float x){
  float ax = fabsf(x) * 0.70710678118654752f;
  float t  = rcpf(1.0f + 0.47047f*ax);
  float p  = t*(0.3480242f + t*(-0.0958798f + t*0.7478556f));
  float er = 1.0f - p*__expf(-ax*ax);
  er = copysignf(er, x);
  return 0.5f*x*(1.0f + er);
}

// ws layout (ushort): hi block, tokbf, then lo block at +LO_OFS
#define LO_OFS 58048
__global__ void tst_transpose(const float* __restrict__ Wg,
                              const float* __restrict__ Wqkv,
                              const float* __restrict__ Wout,
                              const float* __restrict__ W1,
                              const float* __restrict__ W2,
                              const float* __restrict__ tok,
                              ushort_t* __restrict__ ws){
  int i = blockIdx.x*256 + threadIdx.x;
  float w;
  if (i < 8192){                 // WgT [64][128] <- Wg[128][64]
    int n = i>>7, k = i&127;  w = Wg[k*64+n];
  } else if (i < 20480){         // WqkvT [192][64]
    int j = i-8192; int n = j>>6, k = j&63; w = Wqkv[k*192+n];
  } else if (i < 24576){         // WoutT [64][64]
    int j = i-20480; int n = j>>6, k = j&63; w = Wout[k*64+n];
  } else if (i < 40960){         // W1T [256][64]
    int j = i-24576; int n = j>>6, k = j&63; w = W1[k*256+n];
  } else if (i < 57344){         // W2T [64][256]
    int j = i-40960; int n = j>>8, k = j&255; w = W2[k*64+n];
  } else if (i < 58048){         // tokbf [11][64] (single)
    ws[i] = f2bf(tok[i-57344]);
    return;
  } else return;
  ushort_t hi = f2bf(w);
  ws[i] = hi;
  ws[i + LO_OFS] = f2bf(w - bf2f(hi));
}

// LDS slot rotation (ushort offsets, row stride 72, 4608 per slot):
//  S0=0      h_hi  -> Q (q pre-scaled by 0.25)
//  S1=4608   h_lo  -> K
//  S2=9216   h' (single) -> E strips -> HID[64][132] (with S3)
//  S3=13824  AT          -> HID upper part
//  S4=18432  VT
#define HB_H  0
#define HB_L  4608
#define HP_H  9216
#define Q_S   0
#define K_S   4608
#define VT_S  18432
#define P_S   9216
#define AT_S  13824
#define HID_S 9216     // stride 132, spans S2+S3
#define POOLN 23040

// LN over rows; y in regs -> hreg + h store into HB.
// SPLIT: hi/lo pair (feeds 3-term G). !SPLIT: hi only (feeds 2-term FFN1).
template<bool SPLIT>
__device__ __forceinline__ void ln_block(float y[4][4], float hreg[4][4],
    const float* gw, const float* bw, ushort_t* pool,
    float* sh_red, float* sh_red2, int col, int lg, int wv, int lc, int tid)
{
  #pragma unroll
  for (int mt=0;mt<4;++mt)
    #pragma unroll
    for (int r=0;r<4;++r){
      float a = y[mt][r], q = a*a;
      #pragma unroll
      for (int o=1;o<16;o<<=1){ a += __shfl_xor(a,o,16); q += __shfl_xor(q,o,16); }
      if (lc == 0){
        int row = mt*16 + lg*4 + r;
        sh_red[row*8 + wv*2]   = a;
        sh_red[row*8 + wv*2+1] = q;
      }
    }
  __syncthreads();
  if (tid < 64){
    float a = sh_red[tid*8]+sh_red[tid*8+2]+sh_red[tid*8+4]+sh_red[tid*8+6];
    float q = sh_red[tid*8+1]+sh_red[tid*8+3]+sh_red[tid*8+5]+sh_red[tid*8+7];
    float mean = a*(1.f/64.f);
    float var  = fmaxf(q*(1.f/64.f) - mean*mean, 0.f);
    sh_red2[tid*2]   = mean;
    sh_red2[tid*2+1] = rsqrtf(var + 1e-5f);
  }
  __syncthreads();
  float gc = gw[col], bc = bw[col];
  #pragma unroll
  for (int mt=0;mt<4;++mt)
    #pragma unroll
    for (int r=0;r<4;++r){
      int row = mt*16 + lg*4 + r;
      float hn = (y[mt][r] - sh_red2[row*2])*sh_red2[row*2+1]*gc + bc;
      hreg[mt][r] = hn;
      if (SPLIT) st2(pool + HB_H, pool + HB_L, row*72 + col, hn);
      else       pool[HB_H + row*72 + col] = f2bf(hn);
    }
}

__global__ __launch_bounds__(256,3) void tst_main(
    const int* __restrict__ xin, const int* __restrict__ out_pos,
    const float* __restrict__ tok, const float* __restrict__ ope,
    const float* __restrict__ stepe, const float* __restrict__ rel,
    const float* __restrict__ bg, const float* __restrict__ bqkv,
    const float* __restrict__ bout, const float* __restrict__ b1,
    const float* __restrict__ b2,
    const float* __restrict__ ln1g, const float* __restrict__ ln1b,
    const float* __restrict__ ln2g, const float* __restrict__ ln2b,
    const float* __restrict__ lnog, const float* __restrict__ lnob,
    const float* __restrict__ Wp, const float* __restrict__ bp,
    const float* __restrict__ Wv, const float* __restrict__ bv,
    const ushort_t* __restrict__ ws, float* __restrict__ outp)
{
  __shared__ __align__(16) ushort_t pool[POOLN];
  __shared__ float sh_rel[128];
  __shared__ int   sh_x[64];
  __shared__ float sh_red[64*8];
  __shared__ float sh_red2[64*2];

  const int b    = blockIdx.x;
  const int tid  = threadIdx.x;
  const int lane = tid & 63;
  const int wv   = tid >> 6;
  const int lc   = lane & 15;
  const int lg   = lane >> 4;
  const int col  = wv*16 + lc;

  const ushort_t* WgT_h   = ws;
  const ushort_t* WqkvT_h = ws + 8192;
  const ushort_t* WoutT_h = ws + 20480;
  const ushort_t* W1T_h   = ws + 24576;
  const ushort_t* W2T_h   = ws + 40960;
  const ushort_t* tokbf   = ws + 57344;
  const ushort_t* WgT_l   = ws + LO_OFS;
  const ushort_t* WqkvT_l = ws + LO_OFS + 8192;
  const ushort_t* WoutT_l = ws + LO_OFS + 20480;
  const ushort_t* W1T_l   = ws + LO_OFS + 24576;
  const ushort_t* W2T_l   = ws + LO_OFS + 40960;

  if (tid < 64) sh_x[tid] = xin[b*64 + tid];
  if (tid >= 128 && tid < 255) sh_rel[tid-128] = rel[tid-128];
  __syncthreads();

  int op = out_pos[0]; if (op > 63) op = 63; if (op < 0) op = 0;

  float hreg[4][4];
  float ogv[4][4];     // orig (step-invariant), registers
  {
    float opec = ope[op*64 + col];
    #pragma unroll
    for (int mt=0;mt<4;++mt)
      #pragma unroll
      for (int r=0;r<4;++r){
        int row = mt*16 + lg*4 + r;
        ogv[mt][r] = bf2f(tokbf[sh_x[row]*64 + col]);
        float v = tok[sh_x[row]*64 + col] + opec;
        hreg[mt][r] = v;
        st2(pool + HB_H, pool + HB_L, row*72 + col, v);
      }
  }
  __syncthreads();

  for (int step=0; step<20; ++step){
    // ---- G: gate = sigmoid([h|orig] @ Wg + bg); h' = h*(1-g)+orig*g+emb ----
    {
      floatx4 acc[4];
      float bgc = bg[col];
      #pragma unroll
      for (int mt=0;mt<4;++mt){ acc[mt][0]=bgc;acc[mt][1]=bgc;acc[mt][2]=bgc;acc[mt][3]=bgc; }
      PRIO1();
      #pragma unroll
      for (int kc=0; kc<2; ++kc){      // h half: 3-term split
        int bofs = col*128 + kc*32 + lg*8;
        short8 Bh = LD8(WgT_h, bofs), Bl = LD8(WgT_l, bofs);
        #pragma unroll
        for (int mt=0;mt<4;++mt){
          int aofs = (mt*16+lc)*72 + kc*32 + lg*8;
          short8 Ah = LD8(pool + HB_H, aofs), Al = LD8(pool + HB_L, aofs);
          acc[mt] = MFMA(Ah, Bh, acc[mt]);
          acc[mt] = MFMA(Ah, Bl, acc[mt]);
          acc[mt] = MFMA(Al, Bh, acc[mt]);
        }
      }
      #pragma unroll
      for (int kc=2; kc<4; ++kc){      // orig half: single-term, from global
        int bofs = col*128 + kc*32 + lg*8;
        short8 Bh = LD8(WgT_h, bofs);
        #pragma unroll
        for (int mt=0;mt<4;++mt){
          short8 A = LD8(tokbf, sh_x[mt*16+lc]*64 + (kc-2)*32 + lg*8);
          acc[mt] = MFMA(A, Bh, acc[mt]);
        }
      }
      PRIO0();
      float embc = stepe[step*64 + col];
      #pragma unroll
      for (int mt=0;mt<4;++mt)
        #pragma unroll
        for (int r=0;r<4;++r){
          int row = mt*16 + lg*4 + r;
          float g = rcpf(1.f + __expf(-acc[mt][r]));
          float nh = hreg[mt][r]*(1.f-g) + ogv[mt][r]*g + embc;
          hreg[mt][r] = nh;
          pool[HP_H + row*72 + col] = f2bf(nh);   // h' single
        }
    }
    __syncthreads();

    // ---- QKV: h' @ Wqkv + bqkv (2-term); Q (x0.25) ->S0, K->S1, VT->S4 ----
    #pragma unroll 1
    for (int p=0;p<3;++p){
      float bqc = bqkv[p*64 + col];
      floatx4 aq[4];
      #pragma unroll
      for (int mt=0;mt<4;++mt){ aq[mt][0]=bqc;aq[mt][1]=bqc;aq[mt][2]=bqc;aq[mt][3]=bqc; }
      PRIO1();
      #pragma unroll
      for (int kc=0;kc<2;++kc){
        int bofs = (p*64 + col)*64 + kc*32 + lg*8;
        short8 Bh = LD8(WqkvT_h, bofs), Bl = LD8(WqkvT_l, bofs);
        #pragma unroll
        for (int mt=0;mt<4;++mt){
          int aofs = (mt*16+lc)*72 + kc*32 + lg*8;
          short8 Ah = LD8(pool + HP_H, aofs);
          aq[mt] = MFMA(Ah, Bh, aq[mt]);
          aq[mt] = MFMA(Ah, Bl, aq[mt]);
        }
      }
      PRIO0();
      #pragma unroll
      for (int mt=0;mt<4;++mt)
        #pragma unroll
        for (int r=0;r<4;++r){
          int row = mt*16 + lg*4 + r;
          if (p==0)      pool[Q_S  + row*72 + col] = f2bf(aq[mt][r]*0.25f);
          else if (p==1) pool[K_S  + row*72 + col] = f2bf(aq[mt][r]);
          else           pool[VT_S + col*72 + row] = f2bf(aq[mt][r]);
        }
    }
    __syncthreads();

    // ---- attention: wave wv owns row-quarter [16wv,16wv+16), all heads ----
    // Unnormalized E = exp(s+bias) (shift-free: |s|<<88); row-sum via
    // es = E@ones MFMA (no shuffles); attn = (E@V) * rcp(es).
    {
      const int rbase = 16*wv + lg*4;
      const short8 onesv = ones8bf();
      #pragma unroll 1
      for (int hd=0; hd<4; ++hd){
        short8 Aq = zero8();
        if (lg < 2) Aq = LD8(pool+Q_S, (16*wv+lc)*72 + hd*16 + lg*8);
        floatx4 sa[4];
        PRIO1();
        #pragma unroll
        for (int nt=0;nt<4;++nt){
          short8 Bk = zero8();
          if (lg < 2) Bk = LD8(pool+K_S, (nt*16+lc)*72 + hd*16 + lg*8);
          floatx4 z; z[0]=0;z[1]=0;z[2]=0;z[3]=0;
          sa[nt] = MFMA(Aq, Bk, z);
        }
        PRIO0();
        #pragma unroll
        for (int r=0;r<4;++r){
          int bidx = rbase + r + 63 - lc;
          int prow = (rbase + r)*72 + lc;
          pool[P_S + prow     ] = f2bf(__expf(sa[0][r] + sh_rel[bidx]));
          pool[P_S + prow + 16] = f2bf(__expf(sa[1][r] + sh_rel[bidx-16]));
          pool[P_S + prow + 32] = f2bf(__expf(sa[2][r] + sh_rel[bidx-32]));
          pool[P_S + prow + 48] = f2bf(__expf(sa[3][r] + sh_rel[bidx-48]));
        }
        floatx4 pa; pa[0]=0;pa[1]=0;pa[2]=0;pa[3]=0;
        floatx4 es; es[0]=0;es[1]=0;es[2]=0;es[3]=0;
        PRIO1();
        #pragma unroll
        for (int kc=0;kc<2;++kc){
          short8 Ap = LD8(pool+P_S,  (16*wv+lc)*72 + kc*32 + lg*8);
          short8 Bv = LD8(pool+VT_S, (hd*16+lc)*72 + kc*32 + lg*8);
          pa = MFMA(Ap, Bv, pa);
          es = MFMA(Ap, onesv, es);
        }
        PRIO0();
        #pragma unroll
        for (int r=0;r<4;++r)
          pool[AT_S + (rbase + r)*72 + hd*16 + lc] = f2bf(pa[r]*rcpf(es[r]));
      }
    }
    __syncthreads();

    // ---- proj: h = LN1(h' + attn @ Wout + bout), 2-term; LN1 -> single ----
    {
      floatx4 pj[4];
      float boc = bout[col];
      #pragma unroll
      for (int mt=0;mt<4;++mt){ pj[mt][0]=boc;pj[mt][1]=boc;pj[mt][2]=boc;pj[mt][3]=boc; }
      PRIO1();
      #pragma unroll
      for (int kc=0;kc<2;++kc){
        int bofs = col*64 + kc*32 + lg*8;
        short8 Bh = LD8(WoutT_h, bofs), Bl = LD8(WoutT_l, bofs);
        #pragma unroll
        for (int mt=0;mt<4;++mt){
          short8 A = LD8(pool+AT_S, (mt*16+lc)*72 + kc*32 + lg*8);
          pj[mt] = MFMA(A, Bh, pj[mt]);
          pj[mt] = MFMA(A, Bl, pj[mt]);
        }
      }
      PRIO0();
      float y[4][4];
      #pragma unroll
      for (int mt=0;mt<4;++mt)
        #pragma unroll
        for (int r=0;r<4;++r) y[mt][r] = hreg[mt][r] + pj[mt][r];
      ln_block<false>(y, hreg, ln1g, ln1b, pool, sh_red, sh_red2, col, lg, wv, lc, tid);
    }
    __syncthreads();

    // ---- FFN, two 128-wide halves; f2 accumulated in regs across halves ----
    {
      floatx4 f2a[4];
      float b2c = b2[col];
      #pragma unroll
      for (int mt=0;mt<4;++mt){ f2a[mt][0]=b2c;f2a[mt][1]=b2c;f2a[mt][2]=b2c;f2a[mt][3]=b2c; }
      #pragma unroll 1
      for (int ph=0; ph<2; ++ph){
        // FFN1 half: hid = gelu(h @ W1 + b1), 2-term (h single in LDS)
        #pragma unroll 1
        for (int pp=0; pp<2; ++pp){
          int ch = ph*128 + pp*64 + wv*16 + lc;    // hidden col
          float b1c = b1[ch];
          floatx4 f1[4];
          #pragma unroll
          for (int mt=0;mt<4;++mt){ f1[mt][0]=b1c;f1[mt][1]=b1c;f1[mt][2]=b1c;f1[mt][3]=b1c; }
          PRIO1();
          #pragma unroll
          for (int kc=0;kc<2;++kc){
            int b0 = ch*64 + kc*32 + lg*8;
            short8 Bh0 = LD8(W1T_h, b0), Bl0 = LD8(W1T_l, b0);
            #pragma unroll
            for (int mt=0;mt<4;++mt){
              int aofs = (mt*16+lc)*72 + kc*32 + lg*8;
              short8 Ah = LD8(pool + HB_H, aofs);
              f1[mt] = MFMA(Ah, Bh0, f1[mt]);
              f1[mt] = MFMA(Ah, Bl0, f1[mt]);
            }
          }
          PRIO0();
          #pragma unroll
          for (int mt=0;mt<4;++mt)
            #pragma unroll
            for (int r=0;r<4;++r){
              int row = mt*16 + lg*4 + r;
              pool[HID_S + row*132 + pp*64 + wv*16 + lc] = f2bf(gelu_f(f1[mt][r]));
            }
        }
        __syncthreads();
        // FFN2 accum half: f2 += hid @ W2[half]
        PRIO1();
        #pragma unroll
        for (int kc=0;kc<4;++kc){
          int bofs = col*256 + ph*128 + kc*32 + lg*8;
          short8 Bh = LD8(W2T_h, bofs), Bl = LD8(W2T_l, bofs);
          #pragma unroll
          for (int mt=0;mt<4;++mt){
            short8 A = LD8(pool+HID_S, (mt*16+lc)*132 + kc*32 + lg*8);
            f2a[mt] = MFMA(A, Bh, f2a[mt]);
            f2a[mt] = MFMA(A, Bl, f2a[mt]);
          }
        }
        PRIO0();
        __syncthreads();   // before half1 overwrites HID / before ln2 epoch
      }
      float y[4][4];
      #pragma unroll
      for (int mt=0;mt<4;++mt)
        #pragma unroll
        for (int r=0;r<4;++r) y[mt][r] = hreg[mt][r] + f2a[mt][r];
      ln_block<true>(y, hreg, ln2g, ln2b, pool, sh_red, sh_red2, col, lg, wv, lc, tid);
    }
    __syncthreads();
  } // steps

  // ---- epilogue: h_out = LN(h, lno); pooled; policy/value ----
  {
    #pragma unroll
    for (int mt=0;mt<4;++mt)
      #pragma unroll
      for (int r=0;r<4;++r){
        float a = hreg[mt][r], q = a*a;
        #pragma unroll
        for (int o=1;o<16;o<<=1){ a += __shfl_xor(a,o,16); q += __shfl_xor(q,o,16); }
        if (lc == 0){
          int row = mt*16 + lg*4 + r;
          sh_red[row*8 + wv*2]   = a;
          sh_red[row*8 + wv*2+1] = q;
        }
      }
    __syncthreads();
    if (tid < 64){
      float a = sh_red[tid*8]+sh_red[tid*8+2]+sh_red[tid*8+4]+sh_red[tid*8+6];
      float q = sh_red[tid*8+1]+sh_red[tid*8+3]+sh_red[tid*8+5]+sh_red[tid*8+7];
      float mean = a*(1.f/64.f);
      float var  = fmaxf(q*(1.f/64.f) - mean*mean, 0.f);
      sh_red2[tid*2]   = mean;
      sh_red2[tid*2+1] = rsqrtf(var + 1e-5f);
    }
    __syncthreads();
    float gc = lnog[col], bc = lnob[col];
    float psum = 0.f;
    #pragma unroll
    for (int mt=0;mt<4;++mt)
      #pragma unroll
      for (int r=0;r<4;++r){
        int row = mt*16 + lg*4 + r;
        float hn = (hreg[mt][r] - sh_red2[row*2])*sh_red2[row*2+1]*gc + bc;
        outp[22528 + (size_t)b*4096 + row*64 + col] = hn;
        psum += hn;
      }
    sh_red[(wv*16+lc)*4 + lg] = psum;
    __syncthreads();
    if (tid < 64){
      float p = sh_red[tid*4] + sh_red[tid*4+1] + sh_red[tid*4+2] + sh_red[tid*4+3];
      sh_red2[tid] = p * (1.f/64.f);
    }
    __syncthreads();
    if (tid < 10){
      float a = bp[tid];
      for (int d2=0; d2<64; ++d2) a += sh_red2[d2]*Wp[d2*10+tid];
      outp[(size_t)b*10 + tid] = a;
    }
    if (tid == 16){
      float a = bv[0];
      for (int d2=0; d2<64; ++d2) a += sh_red2[d2]*Wv[d2];
      outp[20480 + (size_t)b] = a;
    }
  }
}

extern "C" void kernel_launch(void* const* d_in, const int* in_sizes, int n_in,
                              void* d_out, int out_size, void* d_ws, size_t ws_size,
                              hipStream_t stream) {
  const int*   x       = (const int*)d_in[0];
  const int*   out_pos = (const int*)d_in[1];
  const float* tok     = (const float*)d_in[2];
  const float* ope     = (const float*)d_in[3];
  const float* stepe   = (const float*)d_in[4];
  const float* rel     = (const float*)d_in[5];
  const float* Wg      = (const float*)d_in[6];
  const float* bg      = (const float*)d_in[7];
  const float* Wqkv    = (const float*)d_in[8];
  const float* bqkv    = (const float*)d_in[9];
  const float* Wout    = (const float*)d_in[10];
  const float* bout    = (const float*)d_in[11];
  const float* W1      = (const float*)d_in[12];
  const float* b1      = (const float*)d_in[13];
  const float* W2      = (const float*)d_in[14];
  const float* b2      = (const float*)d_in[15];
  const float* ln1g    = (const float*)d_in[16];
  const float* ln1b    = (const float*)d_in[17];
  const float* ln2g    = (const float*)d_in[18];
  const float* ln2b    = (const float*)d_in[19];
  const float* lnog    = (const float*)d_in[20];
  const float* lnob    = (const float*)d_in[21];
  const float* Wp      = (const float*)d_in[22];
  const float* bp      = (const float*)d_in[23];
  const float* Wv      = (const float*)d_in[24];
  const float* bv      = (const float*)d_in[25];
  ushort_t* ws  = (ushort_t*)d_ws;
  float*    out = (float*)d_out;

  tst_transpose<<<227, 256, 0, stream>>>(Wg, Wqkv, Wout, W1, W2, tok, ws);
  tst_main<<<2048, 256, 0, stream>>>(x, out_pos, tok, ope, stepe, rel,
      bg, bqkv, bout, b1, b2, ln1g, ln1b, ln2g, ln2b, lnog, lnob,
      Wp, bp, Wv, bv, ws, out);
}

// Round 23
// 1938.834 us; speedup vs baseline: 1.0139x; 1.0139x over previous
//
#include <hip/hip_runtime.h>
#include <hip/hip_bf16.h>

// ThinkSortTransformer fused kernel, MI355X (gfx950). FINAL (= r19/r21).
// A/B history: r22 (-gbase) was neutral-to-negative (spill not on critical
// path); r20 restructures regressed 30%. This configuration is the measured
// optimum: best 1943us, steady 2162us, absmax 0.046875 (threshold 0.1056).
// Inputs f32, output f32. One batch per 256-thread block, LDS ~49KB ->
// 3 blocks/CU (launch_bounds(256,3)). Softmax row-sum via MFMA (E@ones);
// unnormalized E (shift-invariant, |s|<<88); normalize after PV with rcp.
// Step-invariant gate base; setprio; rcp sigmoid; SCALE folded into q.
// h bf16 hi/lo -> G 3-term; QKV/FFN 2-term.

typedef unsigned short ushort_t;
using short8  = __attribute__((ext_vector_type(8))) short;
using floatx4 = __attribute__((ext_vector_type(4))) float;

#define MFMA(a,b,c) __builtin_amdgcn_mfma_f32_16x16x32_bf16((a),(b),(c),0,0,0)
#define LD8(base, idx) (*(const short8*)((base) + (idx)))
#define PRIO1() __builtin_amdgcn_s_setprio(1)
#define PRIO0() __builtin_amdgcn_s_setprio(0)

__device__ __forceinline__ float bf2f(ushort_t u){ return __uint_as_float(((unsigned)u)<<16); }
__device__ __forceinline__ ushort_t f2bf(float f){
  unsigned u = __float_as_uint(f);
  u += 0x7fffu + ((u>>16)&1u);           // round-to-nearest-even
  return (ushort_t)(u>>16);
}
__device__ __forceinline__ float rcpf(float x){ return __builtin_amdgcn_rcpf(x); }
// split-store: hi + lo bf16 (self-correcting: lo = RNE(x - hi))
__device__ __forceinline__ void st2(ushort_t* ph, ushort_t* pl, int idx, float x){
  ushort_t h = f2bf(x);
  ph[idx] = h;
  pl[idx] = f2bf(x - bf2f(h));
}
__device__ __forceinline__ short8 zero8(){
  short8 v; v[0]=0;v[1]=0;v[2]=0;v[3]=0;v[4]=0;v[5]=0;v[6]=0;v[7]=0; return v;
}
__device__ __forceinline__ short8 ones8bf(){
  short8 v;
  #pragma unroll
  for (int e=0;e<8;++e) v[e] = (short)0x3F80;   // bf16 1.0
  return v;
}
// GELU via Abramowitz-Stegun 7.1.25 erf approx (|err| <= 2.5e-5 << bf16 eps)
__device__ __forceinline__ float gelu_f(float x){
  float ax = fabsf(x) * 0.70710678118654752f;
  float t  = rcpf(1.0f + 0.47047f*ax);
  float p  = t*(0.3480242f + t*(-0.0958798f + t*0.7478556f));
  float er = 1.0f - p*__expf(-ax*ax);
  er = copysignf(er, x);
  return 0.5f*x*(1.0f + er);
}

// ws layout (ushort): hi block, tokbf, then lo block at +LO_OFS
#define LO_OFS 58048
__global__ void tst_transpose(const float* __restrict__ Wg,
                              const float* __restrict__ Wqkv,
                              const float* __restrict__ Wout,
                              const float* __restrict__ W1,
                              const float* __restrict__ W2,
                              const float* __restrict__ tok,
                              ushort_t* __restrict__ ws){
  int i = blockIdx.x*256 + threadIdx.x;
  float w;
  if (i < 8192){                 // WgT [64][128] <- Wg[128][64]
    int n = i>>7, k = i&127;  w = Wg[k*64+n];
  } else if (i < 20480){         // WqkvT [192][64]
    int j = i-8192; int n = j>>6, k = j&63; w = Wqkv[k*192+n];
  } else if (i < 24576){         // WoutT [64][64]
    int j = i-20480; int n = j>>6, k = j&63; w = Wout[k*64+n];
  } else if (i < 40960){         // W1T [256][64]
    int j = i-24576; int n = j>>6, k = j&63; w = W1[k*256+n];
  } else if (i < 57344){         // W2T [64][256]
    int j = i-40960; int n = j>>8, k = j&255; w = W2[k*64+n];
  } else if (i < 58048){         // tokbf [11][64] (single)
    ws[i] = f2bf(tok[i-57344]);
    return;
  } else return;
  ushort_t hi = f2bf(w);
  ws[i] = hi;
  ws[i + LO_OFS] = f2bf(w - bf2f(hi));
}

// LDS slot rotation (ushort offsets, row stride 72, 4608 per slot):
//  S0=0      h_hi  -> Q (q pre-scaled by 0.25)
//  S1=4608   h_lo  -> K
//  S2=9216   h' (single) -> E strips -> HID[64][132] (with S3)
//  S3=13824  AT          -> HID upper part
//  S4=18432  VT
#define HB_H  0
#define HB_L  4608
#define HP_H  9216
#define Q_S   0
#define K_S   4608
#define VT_S  18432
#define P_S   9216
#define AT_S  13824
#define HID_S 9216     // stride 132, spans S2+S3
#define POOLN 23040

// LN over rows; y in regs -> hreg + h store into HB.
// SPLIT: hi/lo pair (feeds 3-term G). !SPLIT: hi only (feeds 2-term FFN1).
template<bool SPLIT>
__device__ __forceinline__ void ln_block(float y[4][4], float hreg[4][4],
    const float* gw, const float* bw, ushort_t* pool,
    float* sh_red, float* sh_red2, int col, int lg, int wv, int lc, int tid)
{
  #pragma unroll
  for (int mt=0;mt<4;++mt)
    #pragma unroll
    for (int r=0;r<4;++r){
      float a = y[mt][r], q = a*a;
      #pragma unroll
      for (int o=1;o<16;o<<=1){ a += __shfl_xor(a,o,16); q += __shfl_xor(q,o,16); }
      if (lc == 0){
        int row = mt*16 + lg*4 + r;
        sh_red[row*8 + wv*2]   = a;
        sh_red[row*8 + wv*2+1] = q;
      }
    }
  __syncthreads();
  if (tid < 64){
    float a = sh_red[tid*8]+sh_red[tid*8+2]+sh_red[tid*8+4]+sh_red[tid*8+6];
    float q = sh_red[tid*8+1]+sh_red[tid*8+3]+sh_red[tid*8+5]+sh_red[tid*8+7];
    float mean = a*(1.f/64.f);
    float var  = fmaxf(q*(1.f/64.f) - mean*mean, 0.f);
    sh_red2[tid*2]   = mean;
    sh_red2[tid*2+1] = rsqrtf(var + 1e-5f);
  }
  __syncthreads();
  float gc = gw[col], bc = bw[col];
  #pragma unroll
  for (int mt=0;mt<4;++mt)
    #pragma unroll
    for (int r=0;r<4;++r){
      int row = mt*16 + lg*4 + r;
      float hn = (y[mt][r] - sh_red2[row*2])*sh_red2[row*2+1]*gc + bc;
      hreg[mt][r] = hn;
      if (SPLIT) st2(pool + HB_H, pool + HB_L, row*72 + col, hn);
      else       pool[HB_H + row*72 + col] = f2bf(hn);
    }
}

__global__ __launch_bounds__(256,3) void tst_main(
    const int* __restrict__ xin, const int* __restrict__ out_pos,
    const float* __restrict__ tok, const float* __restrict__ ope,
    const float* __restrict__ stepe, const float* __restrict__ rel,
    const float* __restrict__ bg, const float* __restrict__ bqkv,
    const float* __restrict__ bout, const float* __restrict__ b1,
    const float* __restrict__ b2,
    const float* __restrict__ ln1g, const float* __restrict__ ln1b,
    const float* __restrict__ ln2g, const float* __restrict__ ln2b,
    const float* __restrict__ lnog, const float* __restrict__ lnob,
    const float* __restrict__ Wp, const float* __restrict__ bp,
    const float* __restrict__ Wv, const float* __restrict__ bv,
    const ushort_t* __restrict__ ws, float* __restrict__ outp)
{
  __shared__ __align__(16) ushort_t pool[POOLN];
  __shared__ float sh_rel[128];
  __shared__ int   sh_x[64];
  __shared__ float sh_red[64*8];
  __shared__ float sh_red2[64*2];

  const int b    = blockIdx.x;
  const int tid  = threadIdx.x;
  const int lane = tid & 63;
  const int wv   = tid >> 6;
  const int lc   = lane & 15;
  const int lg   = lane >> 4;
  const int col  = wv*16 + lc;

  const ushort_t* WgT_h   = ws;
  const ushort_t* WqkvT_h = ws + 8192;
  const ushort_t* WoutT_h = ws + 20480;
  const ushort_t* W1T_h   = ws + 24576;
  const ushort_t* W2T_h   = ws + 40960;
  const ushort_t* tokbf   = ws + 57344;
  const ushort_t* WgT_l   = ws + LO_OFS;
  const ushort_t* WqkvT_l = ws + LO_OFS + 8192;
  const ushort_t* WoutT_l = ws + LO_OFS + 20480;
  const ushort_t* W1T_l   = ws + LO_OFS + 24576;
  const ushort_t* W2T_l   = ws + LO_OFS + 40960;

  if (tid < 64) sh_x[tid] = xin[b*64 + tid];
  if (tid >= 128 && tid < 255) sh_rel[tid-128] = rel[tid-128];
  __syncthreads();

  int op = out_pos[0]; if (op > 63) op = 63; if (op < 0) op = 0;

  float hreg[4][4];
  float ogv[4][4];     // orig (step-invariant), registers
  floatx4 gbase[4];    // orig @ Wg[64:128] + bg (step-invariant)
  {
    float opec = ope[op*64 + col];
    #pragma unroll
    for (int mt=0;mt<4;++mt)
      #pragma unroll
      for (int r=0;r<4;++r){
        int row = mt*16 + lg*4 + r;
        ogv[mt][r] = bf2f(tokbf[sh_x[row]*64 + col]);
        float v = tok[sh_x[row]*64 + col] + opec;
        hreg[mt][r] = v;
        st2(pool + HB_H, pool + HB_L, row*72 + col, v);
      }
    float bgc = bg[col];
    #pragma unroll
    for (int mt=0;mt<4;++mt){ gbase[mt][0]=bgc;gbase[mt][1]=bgc;gbase[mt][2]=bgc;gbase[mt][3]=bgc; }
    #pragma unroll
    for (int kc=2; kc<4; ++kc){
      int bofs = col*128 + kc*32 + lg*8;
      short8 Bh = LD8(WgT_h, bofs);
      #pragma unroll
      for (int mt=0;mt<4;++mt){
        short8 A = LD8(tokbf, sh_x[mt*16+lc]*64 + (kc-2)*32 + lg*8);
        gbase[mt] = MFMA(A, Bh, gbase[mt]);
      }
    }
  }
  __syncthreads();

  for (int step=0; step<20; ++step){
    // ---- G: gate = sigmoid(h@Wg1 + gbase); h' = h*(1-g)+orig*g+emb ----
    {
      floatx4 acc[4];
      #pragma unroll
      for (int mt=0;mt<4;++mt) acc[mt] = gbase[mt];
      PRIO1();
      #pragma unroll
      for (int kc=0; kc<2; ++kc){      // h half: 3-term split
        int bofs = col*128 + kc*32 + lg*8;
        short8 Bh = LD8(WgT_h, bofs), Bl = LD8(WgT_l, bofs);
        #pragma unroll
        for (int mt=0;mt<4;++mt){
          int aofs = (mt*16+lc)*72 + kc*32 + lg*8;
          short8 Ah = LD8(pool + HB_H, aofs), Al = LD8(pool + HB_L, aofs);
          acc[mt] = MFMA(Ah, Bh, acc[mt]);
          acc[mt] = MFMA(Ah, Bl, acc[mt]);
          acc[mt] = MFMA(Al, Bh, acc[mt]);
        }
      }
      PRIO0();
      float embc = stepe[step*64 + col];
      #pragma unroll
      for (int mt=0;mt<4;++mt)
        #pragma unroll
        for (int r=0;r<4;++r){
          int row = mt*16 + lg*4 + r;
          float g = rcpf(1.f + __expf(-acc[mt][r]));
          float nh = hreg[mt][r]*(1.f-g) + ogv[mt][r]*g + embc;
          hreg[mt][r] = nh;
          pool[HP_H + row*72 + col] = f2bf(nh);   // h' single
        }
    }
    __syncthreads();

    // ---- QKV: h' @ Wqkv + bqkv (2-term); Q (x0.25) ->S0, K->S1, VT->S4 ----
    #pragma unroll 1
    for (int p=0;p<3;++p){
      float bqc = bqkv[p*64 + col];
      floatx4 aq[4];
      #pragma unroll
      for (int mt=0;mt<4;++mt){ aq[mt][0]=bqc;aq[mt][1]=bqc;aq[mt][2]=bqc;aq[mt][3]=bqc; }
      PRIO1();
      #pragma unroll
      for (int kc=0;kc<2;++kc){
        int bofs = (p*64 + col)*64 + kc*32 + lg*8;
        short8 Bh = LD8(WqkvT_h, bofs), Bl = LD8(WqkvT_l, bofs);
        #pragma unroll
        for (int mt=0;mt<4;++mt){
          int aofs = (mt*16+lc)*72 + kc*32 + lg*8;
          short8 Ah = LD8(pool + HP_H, aofs);
          aq[mt] = MFMA(Ah, Bh, aq[mt]);
          aq[mt] = MFMA(Ah, Bl, aq[mt]);
        }
      }
      PRIO0();
      #pragma unroll
      for (int mt=0;mt<4;++mt)
        #pragma unroll
        for (int r=0;r<4;++r){
          int row = mt*16 + lg*4 + r;
          if (p==0)      pool[Q_S  + row*72 + col] = f2bf(aq[mt][r]*0.25f);
          else if (p==1) pool[K_S  + row*72 + col] = f2bf(aq[mt][r]);
          else           pool[VT_S + col*72 + row] = f2bf(aq[mt][r]);
        }
    }
    __syncthreads();

    // ---- attention: wave wv owns row-quarter [16wv,16wv+16), all heads ----
    // Unnormalized E = exp(s+bias) (shift-free: |s|<<88); row-sum via
    // es = E@ones MFMA (no shuffles); attn = (E@V) * rcp(es).
    {
      const int rbase = 16*wv + lg*4;
      const short8 onesv = ones8bf();
      #pragma unroll 1
      for (int hd=0; hd<4; ++hd){
        short8 Aq = zero8();
        if (lg < 2) Aq = LD8(pool+Q_S, (16*wv+lc)*72 + hd*16 + lg*8);
        floatx4 sa[4];
        PRIO1();
        #pragma unroll
        for (int nt=0;nt<4;++nt){
          short8 Bk = zero8();
          if (lg < 2) Bk = LD8(pool+K_S, (nt*16+lc)*72 + hd*16 + lg*8);
          floatx4 z; z[0]=0;z[1]=0;z[2]=0;z[3]=0;
          sa[nt] = MFMA(Aq, Bk, z);
        }
        PRIO0();
        #pragma unroll
        for (int r=0;r<4;++r){
          int bidx = rbase + r + 63 - lc;
          int prow = (rbase + r)*72 + lc;
          pool[P_S + prow     ] = f2bf(__expf(sa[0][r] + sh_rel[bidx]));
          pool[P_S + prow + 16] = f2bf(__expf(sa[1][r] + sh_rel[bidx-16]));
          pool[P_S + prow + 32] = f2bf(__expf(sa[2][r] + sh_rel[bidx-32]));
          pool[P_S + prow + 48] = f2bf(__expf(sa[3][r] + sh_rel[bidx-48]));
        }
        floatx4 pa; pa[0]=0;pa[1]=0;pa[2]=0;pa[3]=0;
        floatx4 es; es[0]=0;es[1]=0;es[2]=0;es[3]=0;
        PRIO1();
        #pragma unroll
        for (int kc=0;kc<2;++kc){
          short8 Ap = LD8(pool+P_S,  (16*wv+lc)*72 + kc*32 + lg*8);
          short8 Bv = LD8(pool+VT_S, (hd*16+lc)*72 + kc*32 + lg*8);
          pa = MFMA(Ap, Bv, pa);
          es = MFMA(Ap, onesv, es);
        }
        PRIO0();
        #pragma unroll
        for (int r=0;r<4;++r)
          pool[AT_S + (rbase + r)*72 + hd*16 + lc] = f2bf(pa[r]*rcpf(es[r]));
      }
    }
    __syncthreads();

    // ---- proj: h = LN1(h' + attn @ Wout + bout), 2-term; LN1 -> single ----
    {
      floatx4 pj[4];
      float boc = bout[col];
      #pragma unroll
      for (int mt=0;mt<4;++mt){ pj[mt][0]=boc;pj[mt][1]=boc;pj[mt][2]=boc;pj[mt][3]=boc; }
      PRIO1();
      #pragma unroll
      for (int kc=0;kc<2;++kc){
        int bofs = col*64 + kc*32 + lg*8;
        short8 Bh = LD8(WoutT_h, bofs), Bl = LD8(WoutT_l, bofs);
        #pragma unroll
        for (int mt=0;mt<4;++mt){
          short8 A = LD8(pool+AT_S, (mt*16+lc)*72 + kc*32 + lg*8);
          pj[mt] = MFMA(A, Bh, pj[mt]);
          pj[mt] = MFMA(A, Bl, pj[mt]);
        }
      }
      PRIO0();
      float y[4][4];
      #pragma unroll
      for (int mt=0;mt<4;++mt)
        #pragma unroll
        for (int r=0;r<4;++r) y[mt][r] = hreg[mt][r] + pj[mt][r];
      ln_block<false>(y, hreg, ln1g, ln1b, pool, sh_red, sh_red2, col, lg, wv, lc, tid);
    }
    __syncthreads();

    // ---- FFN, two 128-wide halves; f2 accumulated in regs across halves ----
    {
      floatx4 f2a[4];
      float b2c = b2[col];
      #pragma unroll
      for (int mt=0;mt<4;++mt){ f2a[mt][0]=b2c;f2a[mt][1]=b2c;f2a[mt][2]=b2c;f2a[mt][3]=b2c; }
      #pragma unroll 1
      for (int ph=0; ph<2; ++ph){
        // FFN1 half: hid = gelu(h @ W1 + b1), 2-term (h single in LDS)
        #pragma unroll 1
        for (int pp=0; pp<2; ++pp){
          int ch = ph*128 + pp*64 + wv*16 + lc;    // hidden col
          float b1c = b1[ch];
          floatx4 f1[4];
          #pragma unroll
          for (int mt=0;mt<4;++mt){ f1[mt][0]=b1c;f1[mt][1]=b1c;f1[mt][2]=b1c;f1[mt][3]=b1c; }
          PRIO1();
          #pragma unroll
          for (int kc=0;kc<2;++kc){
            int b0 = ch*64 + kc*32 + lg*8;
            short8 Bh0 = LD8(W1T_h, b0), Bl0 = LD8(W1T_l, b0);
            #pragma unroll
            for (int mt=0;mt<4;++mt){
              int aofs = (mt*16+lc)*72 + kc*32 + lg*8;
              short8 Ah = LD8(pool + HB_H, aofs);
              f1[mt] = MFMA(Ah, Bh0, f1[mt]);
              f1[mt] = MFMA(Ah, Bl0, f1[mt]);
            }
          }
          PRIO0();
          #pragma unroll
          for (int mt=0;mt<4;++mt)
            #pragma unroll
            for (int r=0;r<4;++r){
              int row = mt*16 + lg*4 + r;
              pool[HID_S + row*132 + pp*64 + wv*16 + lc] = f2bf(gelu_f(f1[mt][r]));
            }
        }
        __syncthreads();
        // FFN2 accum half: f2 += hid @ W2[half]
        PRIO1();
        #pragma unroll
        for (int kc=0;kc<4;++kc){
          int bofs = col*256 + ph*128 + kc*32 + lg*8;
          short8 Bh = LD8(W2T_h, bofs), Bl = LD8(W2T_l, bofs);
          #pragma unroll
          for (int mt=0;mt<4;++mt){
            short8 A = LD8(pool+HID_S, (mt*16+lc)*132 + kc*32 + lg*8);
            f2a[mt] = MFMA(A, Bh, f2a[mt]);
            f2a[mt] = MFMA(A, Bl, f2a[mt]);
          }
        }
        PRIO0();
        __syncthreads();   // before half1 overwrites HID / before ln2 epoch
      }
      float y[4][4];
      #pragma unroll
      for (int mt=0;mt<4;++mt)
        #pragma unroll
        for (int r=0;r<4;++r) y[mt][r] = hreg[mt][r] + f2a[mt][r];
      ln_block<true>(y, hreg, ln2g, ln2b, pool, sh_red, sh_red2, col, lg, wv, lc, tid);
    }
    __syncthreads();
  } // steps

  // ---- epilogue: h_out = LN(h, lno); pooled; policy/value ----
  {
    #pragma unroll
    for (int mt=0;mt<4;++mt)
      #pragma unroll
      for (int r=0;r<4;++r){
        float a = hreg[mt][r], q = a*a;
        #pragma unroll
        for (int o=1;o<16;o<<=1){ a += __shfl_xor(a,o,16); q += __shfl_xor(q,o,16); }
        if (lc == 0){
          int row = mt*16 + lg*4 + r;
          sh_red[row*8 + wv*2]   = a;
          sh_red[row*8 + wv*2+1] = q;
        }
      }
    __syncthreads();
    if (tid < 64){
      float a = sh_red[tid*8]+sh_red[tid*8+2]+sh_red[tid*8+4]+sh_red[tid*8+6];
      float q = sh_red[tid*8+1]+sh_red[tid*8+3]+sh_red[tid*8+5]+sh_red[tid*8+7];
      float mean = a*(1.f/64.f);
      float var  = fmaxf(q*(1.f/64.f) - mean*mean, 0.f);
      sh_red2[tid*2]   = mean;
      sh_red2[tid*2+1] = rsqrtf(var + 1e-5f);
    }
    __syncthreads();
    float gc = lnog[col], bc = lnob[col];
    float psum = 0.f;
    #pragma unroll
    for (int mt=0;mt<4;++mt)
      #pragma unroll
      for (int r=0;r<4;++r){
        int row = mt*16 + lg*4 + r;
        float hn = (hreg[mt][r] - sh_red2[row*2])*sh_red2[row*2+1]*gc + bc;
        outp[22528 + (size_t)b*4096 + row*64 + col] = hn;
        psum += hn;
      }
    sh_red[(wv*16+lc)*4 + lg] = psum;
    __syncthreads();
    if (tid < 64){
      float p = sh_red[tid*4] + sh_red[tid*4+1] + sh_red[tid*4+2] + sh_red[tid*4+3];
      sh_red2[tid] = p * (1.f/64.f);
    }
    __syncthreads();
    if (tid < 10){
      float a = bp[tid];
      for (int d2=0; d2<64; ++d2) a += sh_red2[d2]*Wp[d2*10+tid];
      outp[(size_t)b*10 + tid] = a;
    }
    if (tid == 16){
      float a = bv[0];
      for (int d2=0; d2<64; ++d2) a += sh_red2[d2]*Wv[d2];
      outp[20480 + (size_t)b] = a;
    }
  }
}

extern "C" void kernel_launch(void* const* d_in, const int* in_sizes, int n_in,
                              void* d_out, int out_size, void* d_ws, size_t ws_size,
                              hipStream_t stream) {
  const int*   x       = (const int*)d_in[0];
  const int*   out_pos = (const int*)d_in[1];
  const float* tok     = (const float*)d_in[2];
  const float* ope     = (const float*)d_in[3];
  const float* stepe   = (const float*)d_in[4];
  const float* rel     = (const float*)d_in[5];
  const float* Wg      = (const float*)d_in[6];
  const float* bg      = (const float*)d_in[7];
  const float* Wqkv    = (const float*)d_in[8];
  const float* bqkv    = (const float*)d_in[9];
  const float* Wout    = (const float*)d_in[10];
  const float* bout    = (const float*)d_in[11];
  const float* W1      = (const float*)d_in[12];
  const float* b1      = (const float*)d_in[13];
  const float* W2      = (const float*)d_in[14];
  const float* b2      = (const float*)d_in[15];
  const float* ln1g    = (const float*)d_in[16];
  const float* ln1b    = (const float*)d_in[17];
  const float* ln2g    = (const float*)d_in[18];
  const float* ln2b    = (const float*)d_in[19];
  const float* lnog    = (const float*)d_in[20];
  const float* lnob    = (const float*)d_in[21];
  const float* Wp      = (const float*)d_in[22];
  const float* bp      = (const float*)d_in[23];
  const float* Wv      = (const float*)d_in[24];
  const float* bv      = (const float*)d_in[25];
  ushort_t* ws  = (ushort_t*)d_ws;
  float*    out = (float*)d_out;

  tst_transpose<<<227, 256, 0, stream>>>(Wg, Wqkv, Wout, W1, W2, tok, ws);
  tst_main<<<2048, 256, 0, stream>>>(x, out_pos, tok, ope, stepe, rel,
      bg, bqkv, bout, b1, b2, ln1g, ln1b, ln2g, ln2b, lnog, lnob,
      Wp, bp, Wv, bv, ws, out);
}